// Round 2
// baseline (146.552 us; speedup 1.0000x reference)
//
#include <hip/hip_runtime.h>

#define DEV_INLINE __device__ __forceinline__

// Problem constants
#define PI_F 3.14159265358979323846f

// ws layout (float offsets)
#define H_OFF     0          // 2048
#define SINO_OFF  2048       // 65536
#define DIFF_OFF  67584      // 65536
#define XIN_OFF   133120     // 65536
#define WF2F_OFF  198656     // 4608 ints (18 groups x 64 lanes x int4)
#define WF1B_OFF  207872     // 4608 ints
#define WF2B_OFF  212480     // 256 ints (B-frag of conv2_backward weights)
#define BUFB_OFF  2314240    // xfp: x_forward PIXEL-MAJOR: [gpos*16 + c2]

typedef short bf16x8 __attribute__((ext_vector_type(8)));
typedef float f32x4 __attribute__((ext_vector_type(4)));

union FragI4 { int4 i4; bf16x8 v; };
union I4U    { int4 i4; int i[4]; };

DEV_INLINE unsigned rne1(float a) {
  unsigned u = __float_as_uint(a);
  return (u + 0x7FFFu + ((u >> 16) & 1u)) >> 16;
}
DEV_INLINE int pack_rne(float a, float b) {
  return (int)(rne1(a) | (rne1(b) << 16));
}

// ---------------------------------------------------------------------------
// K1: fused {fwdproj-direct | h | diff=-sino | wf2f | wf1b | wf2b}.
// fwdproj reads img directly (validity folded into bilinear weights), so it
// has NO dependency on the setup pieces -- all roles run in one dispatch.
// blocks: 0..2047 fwdproj | 2048..2111 h | 2112..2367 diff |
//         2368..2403 wf2f/wf1b | 2404 wf2b
// ---------------------------------------------------------------------------
__global__ __launch_bounds__(256) void k1_fwd_setup(
    const float* __restrict__ img, const float* __restrict__ theta,
    const float* __restrict__ sino_in,
    const float* __restrict__ w2f, const float* __restrict__ w1b,
    const float* __restrict__ w2b,
    float* __restrict__ h, float* __restrict__ diff,
    int* __restrict__ wf2f, int* __restrict__ wf1b, int* __restrict__ wf2b,
    float* __restrict__ sino) {
  const int b = blockIdx.x;
  const int tid = threadIdx.x;
  if (b < 2048) {
    // ---- fan-beam forward projection, direct bilinear on img ----
    __shared__ float part[8][32];
    __shared__ float cs[2];
    const int a = b >> 5;
    const int cell = tid & 31;
    const int chunk = tid >> 5;
    const int d = ((b & 31) << 5) + cell;
    if (tid == 0) {
      float th = theta[a];
      cs[0] = cosf(th);
      cs[1] = sinf(th);
    }
    __syncthreads();
    const float c = cs[0], s = cs[1];
    const float u = ((float)d - 511.5f) * 2.0f;
    const float dxv = -1000.0f * c - u * s;
    const float dyv = -1000.0f * s + u * c;
    const float L = sqrtf(1.0e6f + u * u);
    const float sx = fmaf(500.0f, c, 127.5f);
    const float sy = fmaf(500.0f, s, 127.5f);

    float tlo = 0.0f, thi = 1.0f;
    if (fabsf(dxv) > 1e-6f) {
      float inv = 1.0f / dxv;
      float a0 = (-1.0f - sx) * inv, a1 = (256.0f - sx) * inv;
      tlo = fmaxf(tlo, fminf(a0, a1));
      thi = fminf(thi, fmaxf(a0, a1));
    } else if (sx <= -1.0f || sx >= 256.0f) {
      thi = -1.0f;
    }
    if (fabsf(dyv) > 1e-6f) {
      float inv = 1.0f / dyv;
      float a0 = (-1.0f - sy) * inv, a1 = (256.0f - sy) * inv;
      tlo = fmaxf(tlo, fminf(a0, a1));
      thi = fminf(thi, fmaxf(a0, a1));
    } else if (sy <= -1.0f || sy >= 256.0f) {
      thi = -1.0f;
    }
    int imin = (int)ceilf(tlo * 512.0f - 0.5f) - 1;
    imin = imin < 0 ? 0 : imin;
    int imax = (int)floorf(thi * 512.0f - 0.5f) + 1;
    imax = imax > 511 ? 511 : imax;

    float acc = 0.0f;
    for (int i = imin + chunk; i <= imax; i += 8) {
      float t = ((float)i + 0.5f) * (1.0f / 512.0f);
      float cx = fmaf(t, dxv, sx);
      float cy = fmaf(t, dyv, sy);
      cx = fminf(fmaxf(cx, -1.0f), 256.0f);
      cy = fminf(fmaxf(cy, -1.0f), 256.0f);
      float xf = floorf(cx), yf = floorf(cy);
      float fx = cx - xf, fy = cy - yf;
      int ix = (int)xf;                  // [-1, 256]
      int iy = (int)yf;
      // validity folded into weights: tap (ix) valid iff 0<=ix<=255, etc.
      float wx0 = ((unsigned)ix < 256u) ? (1.0f - fx) : 0.0f;
      float wx1 = ((unsigned)(ix + 1) < 256u) ? fx : 0.0f;
      float wy0 = ((unsigned)iy < 256u) ? (1.0f - fy) : 0.0f;
      float wy1 = ((unsigned)(iy + 1) < 256u) ? fy : 0.0f;
      int ix0 = min(max(ix, 0), 255);
      int ix1 = min(ix + 1, 255);
      int iy0 = min(max(iy, 0), 255);
      int iy1 = min(iy + 1, 255);
      const float* r0 = img + (iy0 << 8);
      const float* r1 = img + (iy1 << 8);
      float h0 = fmaf(wx1, r0[ix1], wx0 * r0[ix0]);
      float h1 = fmaf(wx1, r1[ix1], wx0 * r1[ix0]);
      acc = fmaf(wy0, h0, fmaf(wy1, h1, acc));
    }
    part[chunk][cell] = acc;
    __syncthreads();
    if (tid < 32) {
      float r = 0.0f;
      #pragma unroll
      for (int q = 0; q < 8; ++q) r += part[q][tid];
      sino[a * 1024 + ((b & 31) << 5) + tid] = r * (L * (1.0f / 512.0f));
    }
  } else if (b < 2112) {
    // ---- ramp-filter kernel h ----
    __shared__ float hp[8][32];
    const int hb = b - 2048;
    const int cell = tid & 31;
    const int kq = tid >> 5;
    const int n = hb * 32 + cell;
    float ssum = 0.0f;
    const float ang_scale = PI_F / 1024.0f;
    for (int k = kq * 128; k < kq * 128 + 128; ++k) {
      int m = (k * n) & 2047;             // exact angle reduction mod 2*pi
      ssum += (float)k * __cosf((float)m * ang_scale);
    }
    hp[kq][cell] = ssum;
    __syncthreads();
    if (tid < 32) {
      float S = 0.0f;
      #pragma unroll
      for (int q = 0; q < 8; ++q) S += hp[q][tid];
      int nn = hb * 32 + tid;
      float sgn = (nn & 1) ? -1.0f : 1.0f;
      h[nn] = (S * (1.0f / 512.0f) + sgn) * (1.0f / 2048.0f);
    }
  } else if (b < 2368) {
    int idx = (b - 2112) * 256 + tid;     // < 65536
    diff[idx] = -sino_in[idx];
  } else if (b < 2404) {
    const int bb = b - 2368;              // 0..35
    const bool second = (bb >= 18);
    int idx = (second ? bb - 18 : bb) * 256 + tid;   // < 4608
    int d = idx & 3;
    int L = (idx >> 2) & 63;
    int jm = idx >> 8;                    // 0..17
    int j = jm >> 1, mt = jm & 1;
    int co = mt * 16 + (L & 15);
    int ci0 = (L >> 4) * 8 + 2 * d;
    const float* w = second ? w1b : w2f;
    int v = pack_rne(w[co * 288 + ci0 * 9 + j], w[co * 288 + (ci0 + 1) * 9 + j]);
    (second ? wf1b : wf2f)[idx] = v;
  } else {
    // wf2b B-frag: 256 ints; n>=9 columns zero.
    int d = tid & 3;
    int L = tid >> 2;
    int n = L & 15;
    int k0 = (L >> 4) * 8 + 2 * d;
    float lo = (n < 9) ? w2b[k0 * 9 + n] : 0.0f;
    float hi = (n < 9) ? w2b[(k0 + 1) * 9 + n] : 0.0f;
    wf2b[tid] = pack_rne(lo, hi);
  }
}

// ---------------------------------------------------------------------------
// Ramp filter (R7-verified): k-split x4, atomicAdd into diff (= -sinogram).
// ---------------------------------------------------------------------------
__global__ __launch_bounds__(256) void filt(
    const float* __restrict__ sino_pred, const float* __restrict__ h,
    float* __restrict__ diff) {
  __shared__ __align__(16) float srow[256];
  __shared__ __align__(16) float hext[4104];
  const int a = blockIdx.x >> 2;
  const int q = blockIdx.x & 3;
  const int tid = threadIdx.x;
  const int k0base = q * 256;
  srow[tid] = sino_pred[a * 1024 + k0base + tid];
  for (int n = tid; n < 4104; n += 256) hext[n] = h[(n - 2051) & 2047];
  __syncthreads();
  const int dd0 = tid * 4;
  float acc0 = 0.f, acc1 = 0.f, acc2 = 0.f, acc3 = 0.f;
  #pragma unroll 4
  for (int kk = 0; kk < 256; kk += 4) {
    float4 sv = *reinterpret_cast<const float4*>(&srow[kk]);
    int nb = dd0 + 2048 - k0base - kk;
    float4 hA = *reinterpret_cast<const float4*>(&hext[nb]);
    float4 hB = *reinterpret_cast<const float4*>(&hext[nb + 4]);
    acc0 = fmaf(sv.x, hA.w, acc0); acc0 = fmaf(sv.y, hA.z, acc0);
    acc0 = fmaf(sv.z, hA.y, acc0); acc0 = fmaf(sv.w, hA.x, acc0);
    acc1 = fmaf(sv.x, hB.x, acc1); acc1 = fmaf(sv.y, hA.w, acc1);
    acc1 = fmaf(sv.z, hA.z, acc1); acc1 = fmaf(sv.w, hA.y, acc1);
    acc2 = fmaf(sv.x, hB.y, acc2); acc2 = fmaf(sv.y, hB.x, acc2);
    acc2 = fmaf(sv.z, hA.w, acc2); acc2 = fmaf(sv.w, hA.z, acc2);
    acc3 = fmaf(sv.x, hB.z, acc3); acc3 = fmaf(sv.y, hB.y, acc3);
    acc3 = fmaf(sv.z, hB.x, acc3); acc3 = fmaf(sv.w, hA.w, acc3);
  }
  float* o = diff + a * 1024 + dd0;
  atomicAdd(o + 0, acc0);
  atomicAdd(o + 1, acc1);
  atomicAdd(o + 2, acc2);
  atomicAdd(o + 3, acc3);
}

// ---------------------------------------------------------------------------
// Backprojection, atomic-free: 512 blocks x 512 threads.
// Tile 32x4 px; 4-way angle split across threads; LDS reduce; direct write
//   x_input = img - lam*(pi/64)*acc   (removes 262K atomics + x=img copy).
// ---------------------------------------------------------------------------
__global__ __launch_bounds__(512) void backproj(
    const float* __restrict__ diff, const float* __restrict__ theta,
    const float* __restrict__ lam_p, const float* __restrict__ img,
    float* __restrict__ x_input) {
  __shared__ float cst[64], snt[64];
  __shared__ float part[512];
  const int tid = threadIdx.x;
  if (tid < 64) {
    float th = theta[tid];
    cst[tid] = cosf(th);
    snt[tid] = sinf(th);
  }
  __syncthreads();
  const int tX = (blockIdx.x & 7) << 5;
  const int tY = (blockIdx.x >> 3) << 2;
  const int pl = tid & 127;             // pixel in 32x4 tile
  const int ag = tid >> 7;              // 0..3 angle group
  const int pxi = tX + (pl & 31);
  const int pyi = tY + (pl >> 5);
  const float gx = (float)pxi - 127.5f;
  const float gy = (float)pyi - 127.5f;
  float acc = 0.0f;
  for (int ai = ag * 16; ai < ag * 16 + 16; ++ai) {
    float c = cst[ai], s = snt[ai];
    float xr = gx * c + gy * s;
    float yr = gy * c - gx * s;
    float denom = 500.0f - xr;
    float inv = 1.0f / denom;
    float uu = yr * 1000.0f * inv;
    float wgt = 250000.0f * inv * inv;
    float iu = uu * 0.5f + 511.5f;
    float i0f = floorf(iu);
    float fr = iu - i0f;
    int i0 = (int)i0f;
    int c0 = min(max(i0, 0), 1023);
    int c1 = min(max(i0 + 1, 0), 1023);
    float m0 = (i0 >= 0 && i0 < 1024) ? 1.0f : 0.0f;
    float m1 = (i0 + 1 >= 0 && i0 + 1 < 1024) ? 1.0f : 0.0f;
    const float* row = diff + ai * 1024;
    float v0 = row[c0] * m0;
    float v1 = row[c1] * m1;
    acc += (v0 * (1.0f - fr) + v1 * fr) * wgt;
  }
  part[tid] = acc;
  __syncthreads();
  if (tid < 128) {
    float sum = part[tid] + part[tid + 128] + part[tid + 256] + part[tid + 384];
    int p = ((tY + (tid >> 5)) << 8) + tX + (tid & 31);
    x_input[p] = img[p] - lam_p[0] * 0.04908738521234052f * sum;
  }
}

// ---------------------------------------------------------------------------
// conv12f (R1-verified): conv1f + relu (VALU) + conv2f (MFMA, shared B-frag).
// 32x4 tiles (512 blocks) + group-major LDS layout (all b128 LDS traffic).
// Output PIXEL-MAJOR packed bf16 pairs: xfp[gpos*16 + c2] (int2 stores).
// ---------------------------------------------------------------------------
__global__ __launch_bounds__(256) void conv12f(
    const float* __restrict__ x_input, const float* __restrict__ w1f,
    const int* __restrict__ wf2f, int* __restrict__ xfp) {
  __shared__ float xin[8][36];
  __shared__ __align__(16) int htile[3264];   // 4 groups x 204 px x int4
  const int tid = threadIdx.x;
  const int lane = tid & 63;
  const int wave = tid >> 6;
  const int tX = (blockIdx.x & 7) << 5;
  const int tY = (blockIdx.x >> 3) << 2;

  FragI4 wf[2][9];
  const int4* wfg = (const int4*)wf2f;
  #pragma unroll
  for (int mt = 0; mt < 2; ++mt)
    #pragma unroll
    for (int j = 0; j < 9; ++j) wf[mt][j].i4 = wfg[(j * 2 + mt) * 64 + lane];

  for (int idx = tid; idx < 288; idx += 256) {
    int sy = idx / 36;
    int sx = idx - sy * 36;
    int gy = tY + sy - 2, gx = tX + sx - 2;
    xin[sy][sx] = (gy >= 0 && gy < 256 && gx >= 0 && gx < 256)
                      ? x_input[(gy << 8) + gx] : 0.0f;
  }
  __syncthreads();

  for (int pos = tid; pos < 204; pos += 256) {
    int yy = pos / 34;
    int xx = pos - yy * 34;
    int hy = tY + yy - 1, hx = tX + xx - 1;
    bool hin = (hy >= 0 && hy < 256 && hx >= 0 && hx < 256);
    float v[9];
    #pragma unroll
    for (int dy = 0; dy < 3; ++dy)
      #pragma unroll
      for (int dx = 0; dx < 3; ++dx) v[dy * 3 + dx] = xin[yy + dy][xx + dx];
    int packs[16];
    #pragma unroll
    for (int c2 = 0; c2 < 16; ++c2) {
      float r0 = 0.0f, r1 = 0.0f;
      #pragma unroll
      for (int j = 0; j < 9; ++j) {
        r0 = fmaf(v[j], w1f[(2 * c2) * 9 + j], r0);
        r1 = fmaf(v[j], w1f[(2 * c2 + 1) * 9 + j], r1);
      }
      r0 = hin ? fmaxf(r0, 0.0f) : 0.0f;
      r1 = hin ? fmaxf(r1, 0.0f) : 0.0f;
      packs[c2] = pack_rne(r0, r1);
    }
    #pragma unroll
    for (int g = 0; g < 4; ++g)
      *reinterpret_cast<int4*>(&htile[g * 816 + pos * 4]) =
          make_int4(packs[4 * g], packs[4 * g + 1],
                    packs[4 * g + 2], packs[4 * g + 3]);
  }
  __syncthreads();

  const int y = wave;
  const int n = lane & 15;
  const int q = lane >> 4;
  const int qb = q * 816;
  for (int xt = 0; xt < 2; ++xt) {
    const int x0 = xt << 4;
    f32x4 acc0 = {0.f, 0.f, 0.f, 0.f};
    f32x4 acc1 = {0.f, 0.f, 0.f, 0.f};
    #pragma unroll
    for (int j = 0; j < 9; ++j) {
      int dy = j / 3, dx = j - dy * 3;
      int pb = (y + dy) * 34 + x0 + dx + n;
      FragI4 bf;
      bf.i4 = *reinterpret_cast<const int4*>(&htile[qb + pb * 4]);
      acc0 = __builtin_amdgcn_mfma_f32_16x16x32_bf16(wf[0][j].v, bf.v, acc0, 0, 0, 0);
      acc1 = __builtin_amdgcn_mfma_f32_16x16x32_bf16(wf[1][j].v, bf.v, acc1, 0, 0, 0);
    }
    const int gpos = ((tY + y) << 8) + tX + x0 + n;
    int2* xp = (int2*)(xfp + (gpos << 4));
    xp[q]     = make_int2(pack_rne(acc0[0], acc0[1]), pack_rne(acc0[2], acc0[3]));
    xp[4 + q] = make_int2(pack_rne(acc1[0], acc1[1]), pack_rne(acc1[2], acc1[3]));
  }
}

// ---------------------------------------------------------------------------
// branch_tail (R1-verified): group-major LDS layout [g][px][int4]; all
// fragment traffic is aligned b128/b64. LDS 60.4 KB, 2 blocks/CU.
// ---------------------------------------------------------------------------
__global__ __launch_bounds__(256) void branch_tail(
    const int* __restrict__ xfp, const int* __restrict__ wf1b,
    const int* __restrict__ wf2b, const float* __restrict__ thr_p,
    const float* __restrict__ x_input, float* __restrict__ out) {
  __shared__ __align__(16) int ldsX[8704];   // 4 groups x 544 px x int4
  __shared__ __align__(16) int ldsD[6400];   // 4 groups x 400 px x int4
  float* ldsP = (float*)ldsX;                // aliases ldsX after phase A
  const int tid = threadIdx.x;
  const int lane = tid & 63;
  const int wave = tid >> 6;
  const int branch = blockIdx.x >> 8;
  const int tileb = blockIdx.x & 255;
  const int tX = (tileb & 3) << 6;
  const int tY = (tileb >> 2) << 2;
  const float thr = thr_p[0];
  const bool soft = (branch == 0);

  FragI4 wf[2][9];
  const int4* wfg = (const int4*)wf1b;
  #pragma unroll
  for (int mt = 0; mt < 2; ++mt)
    #pragma unroll
    for (int j = 0; j < 9; ++j) wf[mt][j].i4 = wfg[(j * 2 + mt) * 64 + lane];
  FragI4 wb;
  wb.i4 = ((const int4*)wf2b)[lane];

  // zero D rows 396..399 (read by phase P, never written by phase A)
  if (tid < 16) {
    int g = tid >> 2, px = 396 + (tid & 3);
    *reinterpret_cast<int4*>(&ldsD[g * 1600 + px * 4]) = make_int4(0, 0, 0, 0);
  }

  // staging: <=3 px/thread, 4 int4 global loads + 4 b128 LDS writes each.
  #pragma unroll
  for (int t = 0; t < 3; ++t) {
    int p = tid + t * 256;
    if (p < 544) {
      int sy = p / 68;
      int sx = p - sy * 68;
      int gy = tY + sy - 2, gx = tX + sx - 2;
      bool ok = ((unsigned)gy < 256u) && ((unsigned)gx < 256u);
      I4U w[4];
      if (ok) {
        const int4* src = (const int4*)(xfp + (((gy << 8) + gx) << 4));
        w[0].i4 = src[0]; w[1].i4 = src[1]; w[2].i4 = src[2]; w[3].i4 = src[3];
      } else {
        w[0].i4 = w[1].i4 = w[2].i4 = w[3].i4 = make_int4(0, 0, 0, 0);
      }
      #pragma unroll
      for (int g = 0; g < 4; ++g) {
        if (soft) {
          #pragma unroll
          for (int k = 0; k < 4; ++k) {
            int v = w[g].i[k];
            float lo = __uint_as_float(((unsigned)v) << 16);
            float hi = __uint_as_float(((unsigned)v) & 0xFFFF0000u);
            lo = fmaxf(lo - thr, 0.0f) + fminf(lo + thr, 0.0f);
            hi = fmaxf(hi - thr, 0.0f) + fminf(hi + thr, 0.0f);
            w[g].i[k] = pack_rne(lo, hi);
          }
        }
        *reinterpret_cast<int4*>(&ldsX[g * 2176 + p * 4]) = w[g].i4;
      }
    }
  }
  __syncthreads();

  // phase A: D = relu(conv1b) over region rx -1..64, ry -1..4 (16px units).
  const int n = lane & 15;
  const int q = lane >> 4;
  const int rxtab[5] = {-1, 15, 31, 47, 49};
  for (int t = wave; t < 30; t += 4) {
    int trow = t / 5;
    int ry = trow - 1;
    int rx0 = rxtab[t - trow * 5];
    int rxn = rx0 + n;
    bool inimg = ((unsigned)(tX + rxn) < 256u) && ((unsigned)(tY + ry) < 256u);
    int pxD = (ry + 1) * 66 + rxn + 1;
    f32x4 acc0 = {0.f, 0.f, 0.f, 0.f};
    f32x4 acc1 = {0.f, 0.f, 0.f, 0.f};
    #pragma unroll
    for (int j = 0; j < 9; ++j) {
      int dy = j / 3, dx = j - dy * 3;
      int pb = (ry + 1 + dy) * 68 + rx0 + 1 + dx + n;
      FragI4 bf;
      bf.i4 = *reinterpret_cast<const int4*>(&ldsX[q * 2176 + pb * 4]);
      acc0 = __builtin_amdgcn_mfma_f32_16x16x32_bf16(wf[0][j].v, bf.v, acc0, 0, 0, 0);
      acc1 = __builtin_amdgcn_mfma_f32_16x16x32_bf16(wf[1][j].v, bf.v, acc1, 0, 0, 0);
    }
    float a00 = inimg ? fmaxf(acc0[0], 0.0f) : 0.0f;
    float a01 = inimg ? fmaxf(acc0[1], 0.0f) : 0.0f;
    float a02 = inimg ? fmaxf(acc0[2], 0.0f) : 0.0f;
    float a03 = inimg ? fmaxf(acc0[3], 0.0f) : 0.0f;
    float a10 = inimg ? fmaxf(acc1[0], 0.0f) : 0.0f;
    float a11 = inimg ? fmaxf(acc1[1], 0.0f) : 0.0f;
    float a12 = inimg ? fmaxf(acc1[2], 0.0f) : 0.0f;
    float a13 = inimg ? fmaxf(acc1[3], 0.0f) : 0.0f;
    *reinterpret_cast<int2*>(
        &ldsD[(q >> 1) * 1600 + pxD * 4 + (q & 1) * 2]) =
        make_int2(pack_rne(a00, a01), pack_rne(a02, a03));
    *reinterpret_cast<int2*>(
        &ldsD[(2 + (q >> 1)) * 1600 + pxD * 4 + (q & 1) * 2]) =
        make_int2(pack_rne(a10, a11), pack_rne(a12, a13));
  }
  __syncthreads();

  // phase P: 25 M-tiles of 16 px; one MFMA each (A=D, B=wf2b).
  for (int t = wave; t < 25; t += 4) {
    int pbase = t << 4;
    FragI4 af;
    af.i4 = *reinterpret_cast<const int4*>(&ldsD[q * 1600 + (pbase + n) * 4]);
    f32x4 acc = {0.f, 0.f, 0.f, 0.f};
    acc = __builtin_amdgcn_mfma_f32_16x16x32_bf16(af.v, wb.v, acc, 0, 0, 0);
    #pragma unroll
    for (int r = 0; r < 4; ++r)
      ldsP[(pbase + q * 4 + r) * 17 + n] = acc[r];
  }
  __syncthreads();

  // epilogue: out[p] = sum_j P[p+off(j)][j]
  const int px = tid & 63, py = tid >> 6;
  float acc = 0.0f;
  #pragma unroll
  for (int j = 0; j < 9; ++j) {
    int dy = j / 3, dx = j - dy * 3;
    int rp = (py + dy) * 66 + px + dx;
    acc += ldsP[rp * 17 + j];
  }
  const int p = ((tY + py) << 8) + tX + px;
  if (branch == 0) out[p] = acc;
  else out[65536 + p] = acc - x_input[p];
}

extern "C" void kernel_launch(void* const* d_in, const int* in_sizes, int n_in,
                              void* d_out, int out_size, void* d_ws, size_t ws_size,
                              hipStream_t stream) {
  const float* x       = (const float*)d_in[0];
  const float* theta   = (const float*)d_in[1];
  const float* sino_in = (const float*)d_in[2];
  const float* lam     = (const float*)d_in[3];
  const float* thr     = (const float*)d_in[4];
  const float* w_c1f   = (const float*)d_in[5];
  const float* w_c2f   = (const float*)d_in[6];
  const float* w_c1b   = (const float*)d_in[7];
  const float* w_c2b   = (const float*)d_in[8];
  float* out = (float*)d_out;
  float* ws  = (float*)d_ws;

  float* h         = ws + H_OFF;
  float* sino_pred = ws + SINO_OFF;
  float* diff      = ws + DIFF_OFF;
  float* x_input   = ws + XIN_OFF;
  int*   wf2f      = (int*)(ws + WF2F_OFF);
  int*   wf1b      = (int*)(ws + WF1B_OFF);
  int*   wf2b      = (int*)(ws + WF2B_OFF);
  int*   xfp       = (int*)(ws + BUFB_OFF);      // x_forward, pixel-major bf16

  k1_fwd_setup<<<2405, 256, 0, stream>>>(x, theta, sino_in, w_c2f, w_c1b,
                                         w_c2b, h, diff, wf2f, wf1b, wf2b,
                                         sino_pred);
  filt<<<256, 256, 0, stream>>>(sino_pred, h, diff);
  backproj<<<512, 512, 0, stream>>>(diff, theta, lam, x, x_input);
  conv12f<<<512, 256, 0, stream>>>(x_input, w_c1f, wf2f, xfp);
  branch_tail<<<512, 256, 0, stream>>>(xfp, wf1b, wf2b, thr, x_input, out);
}

// Round 3
// 131.364 us; speedup vs baseline: 1.1156x; 1.1156x over previous
//
#include <hip/hip_runtime.h>

#define DEV_INLINE __device__ __forceinline__

// Problem constants
#define PI_F 3.14159265358979323846f

// ws layout (float offsets)
#define H_OFF     0          // 2048
#define SINO_OFF  2048       // 65536
#define DIFF_OFF  67584      // 65536
#define XIN_OFF   133120     // 65536
#define WF2F_OFF  198656     // 4608 ints (18 groups x 64 lanes x int4)
#define WF1B_OFF  207872     // 4608 ints
#define WF2B_OFF  212480     // 256 ints (B-frag of conv2_backward weights)
#define BUFA_OFF  217088     // quadP lives here (258*258 float4)
#define BUFB_OFF  2314240    // xfp: x_forward PIXEL-MAJOR: [gpos*16 + c2]

typedef short bf16x8 __attribute__((ext_vector_type(8)));
typedef float f32x4 __attribute__((ext_vector_type(4)));

union FragI4 { int4 i4; bf16x8 v; };
union I4U    { int4 i4; int i[4]; };

DEV_INLINE unsigned rne1(float a) {
  unsigned u = __float_as_uint(a);
  return (u + 0x7FFFu + ((u >> 16) & 1u)) >> 16;
}
DEV_INLINE int pack_rne(float a, float b) {
  return (int)(rne1(a) | (rne1(b) << 16));
}

// ---------------------------------------------------------------------------
// Setup: h | diff=-sino | wf2f | wf1b | quadP | wf2b.
// (x_input copy removed -- backproj writes x_input = img - lam*bp directly.)
// blocks: 0..63 h | 64..319 diff | 320..355 wf | 356..616 quadP | 617 wf2b
// ---------------------------------------------------------------------------
__global__ __launch_bounds__(256) void setup_kernel(
    const float* __restrict__ sino_in, const float* __restrict__ w2f,
    const float* __restrict__ w1b, const float* __restrict__ w2b,
    const float* __restrict__ img,
    float* __restrict__ h, float* __restrict__ diff,
    int* __restrict__ wf2f, int* __restrict__ wf1b, int* __restrict__ wf2b,
    float4* __restrict__ quadP) {
  const int b = blockIdx.x;
  const int tid = threadIdx.x;
  if (b < 64) {
    __shared__ float hp[8][32];
    const int cell = tid & 31;
    const int kq = tid >> 5;
    const int n = b * 32 + cell;
    float ssum = 0.0f;
    const float ang_scale = PI_F / 1024.0f;
    for (int k = kq * 128; k < kq * 128 + 128; ++k) {
      int m = (k * n) & 2047;             // exact angle reduction mod 2*pi
      ssum += (float)k * __cosf((float)m * ang_scale);
    }
    hp[kq][cell] = ssum;
    __syncthreads();
    if (tid < 32) {
      float S = 0.0f;
      #pragma unroll
      for (int q = 0; q < 8; ++q) S += hp[q][tid];
      int nn = b * 32 + tid;
      float sgn = (nn & 1) ? -1.0f : 1.0f;
      h[nn] = (S * (1.0f / 512.0f) + sgn) * (1.0f / 2048.0f);
    }
  } else if (b < 320) {
    int idx = (b - 64) * 256 + tid;       // < 65536
    diff[idx] = -sino_in[idx];
  } else if (b < 356) {
    const bool second = (b >= 338);
    int idx = (b - (second ? 338 : 320)) * 256 + tid;   // < 4608
    int d = idx & 3;
    int L = (idx >> 2) & 63;
    int jm = idx >> 8;                    // 0..17
    int j = jm >> 1, mt = jm & 1;
    int co = mt * 16 + (L & 15);
    int ci0 = (L >> 4) * 8 + 2 * d;
    const float* w = second ? w1b : w2f;
    int v = pack_rne(w[co * 288 + ci0 * 9 + j], w[co * 288 + (ci0 + 1) * 9 + j]);
    (second ? wf1b : wf2f)[idx] = v;
  } else if (b < 617) {
    int idx = (b - 356) * 256 + tid;
    if (idx < 258 * 258) {
      int y = idx / 258;
      int x = idx - y * 258;
      float4 v;
      int ay = y - 1, bx = x - 1;          // img coords for P(y,x)
      bool y0ok = (ay >= 0 && ay < 256);
      bool y1ok = (ay + 1 >= 0 && ay + 1 < 256);
      bool x0ok = (bx >= 0 && bx < 256);
      bool x1ok = (bx + 1 >= 0 && bx + 1 < 256);
      v.x = (y0ok && x0ok) ? img[(ay << 8) + bx] : 0.0f;
      v.y = (y0ok && x1ok) ? img[(ay << 8) + bx + 1] : 0.0f;
      v.z = (y1ok && x0ok) ? img[((ay + 1) << 8) + bx] : 0.0f;
      v.w = (y1ok && x1ok) ? img[((ay + 1) << 8) + bx + 1] : 0.0f;
      quadP[idx] = v;
    }
  } else {
    // wf2b B-frag: 256 ints; n>=9 columns zero.
    int d = tid & 3;
    int L = tid >> 2;
    int n = L & 15;
    int k0 = (L >> 4) * 8 + 2 * d;
    float lo = (n < 9) ? w2b[k0 * 9 + n] : 0.0f;
    float hi = (n < 9) ? w2b[(k0 + 1) * 9 + n] : 0.0f;
    wf2b[tid] = pack_rne(lo, hi);
  }
}

// ---------------------------------------------------------------------------
// Fan-beam forward projection, quadP gather, 4-deep unrolled.
// 1024 blocks: 64 angles x 16 det-chunks of 64; 4 t-chunks/thread.
// Per iteration: 4 independent float4 gathers in flight (latency hiding).
// ---------------------------------------------------------------------------
__global__ __launch_bounds__(256) void fwdproj(
    const float4* __restrict__ quadP, const float* __restrict__ theta,
    float* __restrict__ sino) {
  __shared__ float part[4][64];
  __shared__ float cs[2];
  const int tid = threadIdx.x;
  const int a = blockIdx.x >> 4;
  const int cell = tid & 63;
  const int chunk = tid >> 6;            // 0..3
  const int d = ((blockIdx.x & 15) << 6) + cell;
  if (tid == 0) {
    float th = theta[a];
    cs[0] = cosf(th);
    cs[1] = sinf(th);
  }
  __syncthreads();
  const float c = cs[0], s = cs[1];
  const float u = ((float)d - 511.5f) * 2.0f;
  const float dxv = -1000.0f * c - u * s;
  const float dyv = -1000.0f * s + u * c;
  const float sx = fmaf(500.0f, c, 127.5f);
  const float sy = fmaf(500.0f, s, 127.5f);

  float tlo = 0.0f, thi = 1.0f;
  if (fabsf(dxv) > 1e-6f) {
    float inv = 1.0f / dxv;
    float a0 = (-1.0f - sx) * inv, a1 = (256.0f - sx) * inv;
    tlo = fmaxf(tlo, fminf(a0, a1));
    thi = fminf(thi, fmaxf(a0, a1));
  } else if (sx <= -1.0f || sx >= 256.0f) {
    thi = -1.0f;
  }
  if (fabsf(dyv) > 1e-6f) {
    float inv = 1.0f / dyv;
    float a0 = (-1.0f - sy) * inv, a1 = (256.0f - sy) * inv;
    tlo = fmaxf(tlo, fminf(a0, a1));
    thi = fminf(thi, fmaxf(a0, a1));
  } else if (sy <= -1.0f || sy >= 256.0f) {
    thi = -1.0f;
  }
  int imin = (int)ceilf(tlo * 512.0f - 0.5f) - 1;
  imin = imin < 0 ? 0 : imin;
  int imax = (int)floorf(thi * 512.0f - 0.5f) + 1;
  imax = imax > 511 ? 511 : imax;

  float acc = 0.0f;
  for (int i = imin + chunk; i <= imax; i += 16) {
    int idxs[4];
    float fxs[4], fys[4];
    #pragma unroll
    for (int k = 0; k < 4; ++k) {
      float t = ((float)(i + 4 * k) + 0.5f) * (1.0f / 512.0f);
      float cx = fmaf(t, dxv, sx);
      float cy = fmaf(t, dyv, sy);
      cx = fminf(fmaxf(cx, -1.0f), 256.0f);
      cy = fminf(fmaxf(cy, -1.0f), 256.0f);
      float xf = floorf(cx), yf = floorf(cy);
      fxs[k] = cx - xf;
      fys[k] = cy - yf;
      idxs[k] = ((int)yf + 1) * 258 + (int)xf + 1;
    }
    float4 q0 = quadP[idxs[0]];
    float4 q1 = quadP[idxs[1]];
    float4 q2 = quadP[idxs[2]];
    float4 q3 = quadP[idxs[3]];
    {
      float gx = 1.0f - fxs[0], gy = 1.0f - fys[0];
      acc += gy * (gx * q0.x + fxs[0] * q0.y) + fys[0] * (gx * q0.z + fxs[0] * q0.w);
    }
    {
      float m = (i + 4 <= imax) ? 1.0f : 0.0f;
      float gx = 1.0f - fxs[1], gy = 1.0f - fys[1];
      float cv = gy * (gx * q1.x + fxs[1] * q1.y) + fys[1] * (gx * q1.z + fxs[1] * q1.w);
      acc = fmaf(m, cv, acc);
    }
    {
      float m = (i + 8 <= imax) ? 1.0f : 0.0f;
      float gx = 1.0f - fxs[2], gy = 1.0f - fys[2];
      float cv = gy * (gx * q2.x + fxs[2] * q2.y) + fys[2] * (gx * q2.z + fxs[2] * q2.w);
      acc = fmaf(m, cv, acc);
    }
    {
      float m = (i + 12 <= imax) ? 1.0f : 0.0f;
      float gx = 1.0f - fxs[3], gy = 1.0f - fys[3];
      float cv = gy * (gx * q3.x + fxs[3] * q3.y) + fys[3] * (gx * q3.z + fxs[3] * q3.w);
      acc = fmaf(m, cv, acc);
    }
  }
  part[chunk][cell] = acc;
  __syncthreads();
  if (tid < 64) {
    float r = part[0][tid] + part[1][tid] + part[2][tid] + part[3][tid];
    int dr = ((blockIdx.x & 15) << 6) + tid;
    float ur = ((float)dr - 511.5f) * 2.0f;
    float Lr = sqrtf(1.0e6f + ur * ur);
    sino[a * 1024 + dr] = r * (Lr * (1.0f / 512.0f));
  }
}

// ---------------------------------------------------------------------------
// Ramp filter (R7-verified): k-split x4, atomicAdd into diff (= -sinogram).
// ---------------------------------------------------------------------------
__global__ __launch_bounds__(256) void filt(
    const float* __restrict__ sino_pred, const float* __restrict__ h,
    float* __restrict__ diff) {
  __shared__ __align__(16) float srow[256];
  __shared__ __align__(16) float hext[4104];
  const int a = blockIdx.x >> 2;
  const int q = blockIdx.x & 3;
  const int tid = threadIdx.x;
  const int k0base = q * 256;
  srow[tid] = sino_pred[a * 1024 + k0base + tid];
  for (int n = tid; n < 4104; n += 256) hext[n] = h[(n - 2051) & 2047];
  __syncthreads();
  const int dd0 = tid * 4;
  float acc0 = 0.f, acc1 = 0.f, acc2 = 0.f, acc3 = 0.f;
  #pragma unroll 4
  for (int kk = 0; kk < 256; kk += 4) {
    float4 sv = *reinterpret_cast<const float4*>(&srow[kk]);
    int nb = dd0 + 2048 - k0base - kk;
    float4 hA = *reinterpret_cast<const float4*>(&hext[nb]);
    float4 hB = *reinterpret_cast<const float4*>(&hext[nb + 4]);
    acc0 = fmaf(sv.x, hA.w, acc0); acc0 = fmaf(sv.y, hA.z, acc0);
    acc0 = fmaf(sv.z, hA.y, acc0); acc0 = fmaf(sv.w, hA.x, acc0);
    acc1 = fmaf(sv.x, hB.x, acc1); acc1 = fmaf(sv.y, hA.w, acc1);
    acc1 = fmaf(sv.z, hA.z, acc1); acc1 = fmaf(sv.w, hA.y, acc1);
    acc2 = fmaf(sv.x, hB.y, acc2); acc2 = fmaf(sv.y, hB.x, acc2);
    acc2 = fmaf(sv.z, hA.w, acc2); acc2 = fmaf(sv.w, hA.z, acc2);
    acc3 = fmaf(sv.x, hB.z, acc3); acc3 = fmaf(sv.y, hB.y, acc3);
    acc3 = fmaf(sv.z, hB.x, acc3); acc3 = fmaf(sv.w, hA.w, acc3);
  }
  float* o = diff + a * 1024 + dd0;
  atomicAdd(o + 0, acc0);
  atomicAdd(o + 1, acc1);
  atomicAdd(o + 2, acc2);
  atomicAdd(o + 3, acc3);
}

// ---------------------------------------------------------------------------
// Backprojection, atomic-free (R2-verified): 512 blocks x 512 threads.
// Tile 32x4 px; 4-way angle split across threads; LDS reduce; direct write
//   x_input = img - lam*(pi/64)*acc.
// ---------------------------------------------------------------------------
__global__ __launch_bounds__(512) void backproj(
    const float* __restrict__ diff, const float* __restrict__ theta,
    const float* __restrict__ lam_p, const float* __restrict__ img,
    float* __restrict__ x_input) {
  __shared__ float cst[64], snt[64];
  __shared__ float part[512];
  const int tid = threadIdx.x;
  if (tid < 64) {
    float th = theta[tid];
    cst[tid] = cosf(th);
    snt[tid] = sinf(th);
  }
  __syncthreads();
  const int tX = (blockIdx.x & 7) << 5;
  const int tY = (blockIdx.x >> 3) << 2;
  const int pl = tid & 127;             // pixel in 32x4 tile
  const int ag = tid >> 7;              // 0..3 angle group
  const int pxi = tX + (pl & 31);
  const int pyi = tY + (pl >> 5);
  const float gx = (float)pxi - 127.5f;
  const float gy = (float)pyi - 127.5f;
  float acc = 0.0f;
  for (int ai = ag * 16; ai < ag * 16 + 16; ++ai) {
    float c = cst[ai], s = snt[ai];
    float xr = gx * c + gy * s;
    float yr = gy * c - gx * s;
    float denom = 500.0f - xr;
    float inv = 1.0f / denom;
    float uu = yr * 1000.0f * inv;
    float wgt = 250000.0f * inv * inv;
    float iu = uu * 0.5f + 511.5f;
    float i0f = floorf(iu);
    float fr = iu - i0f;
    int i0 = (int)i0f;
    int c0 = min(max(i0, 0), 1023);
    int c1 = min(max(i0 + 1, 0), 1023);
    float m0 = (i0 >= 0 && i0 < 1024) ? 1.0f : 0.0f;
    float m1 = (i0 + 1 >= 0 && i0 + 1 < 1024) ? 1.0f : 0.0f;
    const float* row = diff + ai * 1024;
    float v0 = row[c0] * m0;
    float v1 = row[c1] * m1;
    acc += (v0 * (1.0f - fr) + v1 * fr) * wgt;
  }
  part[tid] = acc;
  __syncthreads();
  if (tid < 128) {
    float sum = part[tid] + part[tid + 128] + part[tid + 256] + part[tid + 384];
    int p = ((tY + (tid >> 5)) << 8) + tX + (tid & 31);
    x_input[p] = img[p] - lam_p[0] * 0.04908738521234052f * sum;
  }
}

// ---------------------------------------------------------------------------
// conv12f (R1-verified): conv1f + relu (VALU) + conv2f (MFMA, shared B-frag).
// 32x4 tiles (512 blocks) + group-major LDS layout (all b128 LDS traffic).
// Output PIXEL-MAJOR packed bf16 pairs: xfp[gpos*16 + c2] (int2 stores).
// ---------------------------------------------------------------------------
__global__ __launch_bounds__(256) void conv12f(
    const float* __restrict__ x_input, const float* __restrict__ w1f,
    const int* __restrict__ wf2f, int* __restrict__ xfp) {
  __shared__ float xin[8][36];
  __shared__ __align__(16) int htile[3264];   // 4 groups x 204 px x int4
  const int tid = threadIdx.x;
  const int lane = tid & 63;
  const int wave = tid >> 6;
  const int tX = (blockIdx.x & 7) << 5;
  const int tY = (blockIdx.x >> 3) << 2;

  FragI4 wf[2][9];
  const int4* wfg = (const int4*)wf2f;
  #pragma unroll
  for (int mt = 0; mt < 2; ++mt)
    #pragma unroll
    for (int j = 0; j < 9; ++j) wf[mt][j].i4 = wfg[(j * 2 + mt) * 64 + lane];

  for (int idx = tid; idx < 288; idx += 256) {
    int sy = idx / 36;
    int sx = idx - sy * 36;
    int gy = tY + sy - 2, gx = tX + sx - 2;
    xin[sy][sx] = (gy >= 0 && gy < 256 && gx >= 0 && gx < 256)
                      ? x_input[(gy << 8) + gx] : 0.0f;
  }
  __syncthreads();

  for (int pos = tid; pos < 204; pos += 256) {
    int yy = pos / 34;
    int xx = pos - yy * 34;
    int hy = tY + yy - 1, hx = tX + xx - 1;
    bool hin = (hy >= 0 && hy < 256 && hx >= 0 && hx < 256);
    float v[9];
    #pragma unroll
    for (int dy = 0; dy < 3; ++dy)
      #pragma unroll
      for (int dx = 0; dx < 3; ++dx) v[dy * 3 + dx] = xin[yy + dy][xx + dx];
    int packs[16];
    #pragma unroll
    for (int c2 = 0; c2 < 16; ++c2) {
      float r0 = 0.0f, r1 = 0.0f;
      #pragma unroll
      for (int j = 0; j < 9; ++j) {
        r0 = fmaf(v[j], w1f[(2 * c2) * 9 + j], r0);
        r1 = fmaf(v[j], w1f[(2 * c2 + 1) * 9 + j], r1);
      }
      r0 = hin ? fmaxf(r0, 0.0f) : 0.0f;
      r1 = hin ? fmaxf(r1, 0.0f) : 0.0f;
      packs[c2] = pack_rne(r0, r1);
    }
    #pragma unroll
    for (int g = 0; g < 4; ++g)
      *reinterpret_cast<int4*>(&htile[g * 816 + pos * 4]) =
          make_int4(packs[4 * g], packs[4 * g + 1],
                    packs[4 * g + 2], packs[4 * g + 3]);
  }
  __syncthreads();

  const int y = wave;
  const int n = lane & 15;
  const int q = lane >> 4;
  const int qb = q * 816;
  for (int xt = 0; xt < 2; ++xt) {
    const int x0 = xt << 4;
    f32x4 acc0 = {0.f, 0.f, 0.f, 0.f};
    f32x4 acc1 = {0.f, 0.f, 0.f, 0.f};
    #pragma unroll
    for (int j = 0; j < 9; ++j) {
      int dy = j / 3, dx = j - dy * 3;
      int pb = (y + dy) * 34 + x0 + dx + n;
      FragI4 bf;
      bf.i4 = *reinterpret_cast<const int4*>(&htile[qb + pb * 4]);
      acc0 = __builtin_amdgcn_mfma_f32_16x16x32_bf16(wf[0][j].v, bf.v, acc0, 0, 0, 0);
      acc1 = __builtin_amdgcn_mfma_f32_16x16x32_bf16(wf[1][j].v, bf.v, acc1, 0, 0, 0);
    }
    const int gpos = ((tY + y) << 8) + tX + x0 + n;
    int2* xp = (int2*)(xfp + (gpos << 4));
    xp[q]     = make_int2(pack_rne(acc0[0], acc0[1]), pack_rne(acc0[2], acc0[3]));
    xp[4 + q] = make_int2(pack_rne(acc1[0], acc1[1]), pack_rne(acc1[2], acc1[3]));
  }
}

// ---------------------------------------------------------------------------
// branch_tail (R1-verified): group-major LDS layout [g][px][int4]; all
// fragment traffic is aligned b128/b64. LDS 60.4 KB, 2 blocks/CU.
// ---------------------------------------------------------------------------
__global__ __launch_bounds__(256) void branch_tail(
    const int* __restrict__ xfp, const int* __restrict__ wf1b,
    const int* __restrict__ wf2b, const float* __restrict__ thr_p,
    const float* __restrict__ x_input, float* __restrict__ out) {
  __shared__ __align__(16) int ldsX[8704];   // 4 groups x 544 px x int4
  __shared__ __align__(16) int ldsD[6400];   // 4 groups x 400 px x int4
  float* ldsP = (float*)ldsX;                // aliases ldsX after phase A
  const int tid = threadIdx.x;
  const int lane = tid & 63;
  const int wave = tid >> 6;
  const int branch = blockIdx.x >> 8;
  const int tileb = blockIdx.x & 255;
  const int tX = (tileb & 3) << 6;
  const int tY = (tileb >> 2) << 2;
  const float thr = thr_p[0];
  const bool soft = (branch == 0);

  FragI4 wf[2][9];
  const int4* wfg = (const int4*)wf1b;
  #pragma unroll
  for (int mt = 0; mt < 2; ++mt)
    #pragma unroll
    for (int j = 0; j < 9; ++j) wf[mt][j].i4 = wfg[(j * 2 + mt) * 64 + lane];
  FragI4 wb;
  wb.i4 = ((const int4*)wf2b)[lane];

  // zero D rows 396..399 (read by phase P, never written by phase A)
  if (tid < 16) {
    int g = tid >> 2, px = 396 + (tid & 3);
    *reinterpret_cast<int4*>(&ldsD[g * 1600 + px * 4]) = make_int4(0, 0, 0, 0);
  }

  // staging: <=3 px/thread, 4 int4 global loads + 4 b128 LDS writes each.
  #pragma unroll
  for (int t = 0; t < 3; ++t) {
    int p = tid + t * 256;
    if (p < 544) {
      int sy = p / 68;
      int sx = p - sy * 68;
      int gy = tY + sy - 2, gx = tX + sx - 2;
      bool ok = ((unsigned)gy < 256u) && ((unsigned)gx < 256u);
      I4U w[4];
      if (ok) {
        const int4* src = (const int4*)(xfp + (((gy << 8) + gx) << 4));
        w[0].i4 = src[0]; w[1].i4 = src[1]; w[2].i4 = src[2]; w[3].i4 = src[3];
      } else {
        w[0].i4 = w[1].i4 = w[2].i4 = w[3].i4 = make_int4(0, 0, 0, 0);
      }
      #pragma unroll
      for (int g = 0; g < 4; ++g) {
        if (soft) {
          #pragma unroll
          for (int k = 0; k < 4; ++k) {
            int v = w[g].i[k];
            float lo = __uint_as_float(((unsigned)v) << 16);
            float hi = __uint_as_float(((unsigned)v) & 0xFFFF0000u);
            lo = fmaxf(lo - thr, 0.0f) + fminf(lo + thr, 0.0f);
            hi = fmaxf(hi - thr, 0.0f) + fminf(hi + thr, 0.0f);
            w[g].i[k] = pack_rne(lo, hi);
          }
        }
        *reinterpret_cast<int4*>(&ldsX[g * 2176 + p * 4]) = w[g].i4;
      }
    }
  }
  __syncthreads();

  // phase A: D = relu(conv1b) over region rx -1..64, ry -1..4 (16px units).
  const int n = lane & 15;
  const int q = lane >> 4;
  const int rxtab[5] = {-1, 15, 31, 47, 49};
  for (int t = wave; t < 30; t += 4) {
    int trow = t / 5;
    int ry = trow - 1;
    int rx0 = rxtab[t - trow * 5];
    int rxn = rx0 + n;
    bool inimg = ((unsigned)(tX + rxn) < 256u) && ((unsigned)(tY + ry) < 256u);
    int pxD = (ry + 1) * 66 + rxn + 1;
    f32x4 acc0 = {0.f, 0.f, 0.f, 0.f};
    f32x4 acc1 = {0.f, 0.f, 0.f, 0.f};
    #pragma unroll
    for (int j = 0; j < 9; ++j) {
      int dy = j / 3, dx = j - dy * 3;
      int pb = (ry + 1 + dy) * 68 + rx0 + 1 + dx + n;
      FragI4 bf;
      bf.i4 = *reinterpret_cast<const int4*>(&ldsX[q * 2176 + pb * 4]);
      acc0 = __builtin_amdgcn_mfma_f32_16x16x32_bf16(wf[0][j].v, bf.v, acc0, 0, 0, 0);
      acc1 = __builtin_amdgcn_mfma_f32_16x16x32_bf16(wf[1][j].v, bf.v, acc1, 0, 0, 0);
    }
    float a00 = inimg ? fmaxf(acc0[0], 0.0f) : 0.0f;
    float a01 = inimg ? fmaxf(acc0[1], 0.0f) : 0.0f;
    float a02 = inimg ? fmaxf(acc0[2], 0.0f) : 0.0f;
    float a03 = inimg ? fmaxf(acc0[3], 0.0f) : 0.0f;
    float a10 = inimg ? fmaxf(acc1[0], 0.0f) : 0.0f;
    float a11 = inimg ? fmaxf(acc1[1], 0.0f) : 0.0f;
    float a12 = inimg ? fmaxf(acc1[2], 0.0f) : 0.0f;
    float a13 = inimg ? fmaxf(acc1[3], 0.0f) : 0.0f;
    *reinterpret_cast<int2*>(
        &ldsD[(q >> 1) * 1600 + pxD * 4 + (q & 1) * 2]) =
        make_int2(pack_rne(a00, a01), pack_rne(a02, a03));
    *reinterpret_cast<int2*>(
        &ldsD[(2 + (q >> 1)) * 1600 + pxD * 4 + (q & 1) * 2]) =
        make_int2(pack_rne(a10, a11), pack_rne(a12, a13));
  }
  __syncthreads();

  // phase P: 25 M-tiles of 16 px; one MFMA each (A=D, B=wf2b).
  for (int t = wave; t < 25; t += 4) {
    int pbase = t << 4;
    FragI4 af;
    af.i4 = *reinterpret_cast<const int4*>(&ldsD[q * 1600 + (pbase + n) * 4]);
    f32x4 acc = {0.f, 0.f, 0.f, 0.f};
    acc = __builtin_amdgcn_mfma_f32_16x16x32_bf16(af.v, wb.v, acc, 0, 0, 0);
    #pragma unroll
    for (int r = 0; r < 4; ++r)
      ldsP[(pbase + q * 4 + r) * 17 + n] = acc[r];
  }
  __syncthreads();

  // epilogue: out[p] = sum_j P[p+off(j)][j]
  const int px = tid & 63, py = tid >> 6;
  float acc = 0.0f;
  #pragma unroll
  for (int j = 0; j < 9; ++j) {
    int dy = j / 3, dx = j - dy * 3;
    int rp = (py + dy) * 66 + px + dx;
    acc += ldsP[rp * 17 + j];
  }
  const int p = ((tY + py) << 8) + tX + px;
  if (branch == 0) out[p] = acc;
  else out[65536 + p] = acc - x_input[p];
}

extern "C" void kernel_launch(void* const* d_in, const int* in_sizes, int n_in,
                              void* d_out, int out_size, void* d_ws, size_t ws_size,
                              hipStream_t stream) {
  const float* x       = (const float*)d_in[0];
  const float* theta   = (const float*)d_in[1];
  const float* sino_in = (const float*)d_in[2];
  const float* lam     = (const float*)d_in[3];
  const float* thr     = (const float*)d_in[4];
  const float* w_c1f   = (const float*)d_in[5];
  const float* w_c2f   = (const float*)d_in[6];
  const float* w_c1b   = (const float*)d_in[7];
  const float* w_c2b   = (const float*)d_in[8];
  float* out = (float*)d_out;
  float* ws  = (float*)d_ws;

  float* h         = ws + H_OFF;
  float* sino_pred = ws + SINO_OFF;
  float* diff      = ws + DIFF_OFF;
  float* x_input   = ws + XIN_OFF;
  int*   wf2f      = (int*)(ws + WF2F_OFF);
  int*   wf1b      = (int*)(ws + WF1B_OFF);
  int*   wf2b      = (int*)(ws + WF2B_OFF);
  float4* quadP    = (float4*)(ws + BUFA_OFF);   // dead once fwdproj completes
  int*   xfp       = (int*)(ws + BUFB_OFF);      // x_forward, pixel-major bf16

  setup_kernel<<<618, 256, 0, stream>>>(sino_in, w_c2f, w_c1b, w_c2b, x, h,
                                        diff, wf2f, wf1b, wf2b, quadP);
  fwdproj<<<1024, 256, 0, stream>>>(quadP, theta, sino_pred);
  filt<<<256, 256, 0, stream>>>(sino_pred, h, diff);
  backproj<<<512, 512, 0, stream>>>(diff, theta, lam, x, x_input);
  conv12f<<<512, 256, 0, stream>>>(x_input, w_c1f, wf2f, xfp);
  branch_tail<<<512, 256, 0, stream>>>(xfp, wf1b, wf2b, thr, x_input, out);
}

// Round 4
// 127.160 us; speedup vs baseline: 1.1525x; 1.0331x over previous
//
#include <hip/hip_runtime.h>

#define DEV_INLINE __device__ __forceinline__

// Problem constants
#define PI_F 3.14159265358979323846f

// ws layout (float offsets)
#define H_OFF     0          // 2048
#define SINO_OFF  2048       // 65536
#define DIFF_OFF  67584      // 65536
#define XIN_OFF   133120     // 65536
#define WF2F_OFF  198656     // 4608 ints (18 groups x 64 lanes x int4)
#define WF1B_OFF  207872     // 4608 ints
#define WF2B_OFF  212480     // 256 ints (B-frag of conv2_backward weights)
#define BUFA_OFF  217088     // quadP lives here (258*258 float4)
#define BUFB_OFF  2314240    // xfp: x_forward PIXEL-MAJOR: [gpos*16 + c2]

typedef short bf16x8 __attribute__((ext_vector_type(8)));
typedef float f32x4 __attribute__((ext_vector_type(4)));

union FragI4 { int4 i4; bf16x8 v; };
union I4U    { int4 i4; int i[4]; };

DEV_INLINE unsigned rne1(float a) {
  unsigned u = __float_as_uint(a);
  return (u + 0x7FFFu + ((u >> 16) & 1u)) >> 16;
}
DEV_INLINE int pack_rne(float a, float b) {
  return (int)(rne1(a) | (rne1(b) << 16));
}

// ---------------------------------------------------------------------------
// Setup: h | diff=-sino | wf2f | wf1b | quadP | wf2b.
// (x_input copy removed -- backproj writes x_input = img - lam*bp directly.)
// blocks: 0..63 h | 64..319 diff | 320..355 wf | 356..616 quadP | 617 wf2b
// ---------------------------------------------------------------------------
__global__ __launch_bounds__(256) void setup_kernel(
    const float* __restrict__ sino_in, const float* __restrict__ w2f,
    const float* __restrict__ w1b, const float* __restrict__ w2b,
    const float* __restrict__ img,
    float* __restrict__ h, float* __restrict__ diff,
    int* __restrict__ wf2f, int* __restrict__ wf1b, int* __restrict__ wf2b,
    float4* __restrict__ quadP) {
  const int b = blockIdx.x;
  const int tid = threadIdx.x;
  if (b < 64) {
    __shared__ float hp[8][32];
    const int cell = tid & 31;
    const int kq = tid >> 5;
    const int n = b * 32 + cell;
    float ssum = 0.0f;
    const float ang_scale = PI_F / 1024.0f;
    for (int k = kq * 128; k < kq * 128 + 128; ++k) {
      int m = (k * n) & 2047;             // exact angle reduction mod 2*pi
      ssum += (float)k * __cosf((float)m * ang_scale);
    }
    hp[kq][cell] = ssum;
    __syncthreads();
    if (tid < 32) {
      float S = 0.0f;
      #pragma unroll
      for (int q = 0; q < 8; ++q) S += hp[q][tid];
      int nn = b * 32 + tid;
      float sgn = (nn & 1) ? -1.0f : 1.0f;
      h[nn] = (S * (1.0f / 512.0f) + sgn) * (1.0f / 2048.0f);
    }
  } else if (b < 320) {
    int idx = (b - 64) * 256 + tid;       // < 65536
    diff[idx] = -sino_in[idx];
  } else if (b < 356) {
    const bool second = (b >= 338);
    int idx = (b - (second ? 338 : 320)) * 256 + tid;   // < 4608
    int d = idx & 3;
    int L = (idx >> 2) & 63;
    int jm = idx >> 8;                    // 0..17
    int j = jm >> 1, mt = jm & 1;
    int co = mt * 16 + (L & 15);
    int ci0 = (L >> 4) * 8 + 2 * d;
    const float* w = second ? w1b : w2f;
    int v = pack_rne(w[co * 288 + ci0 * 9 + j], w[co * 288 + (ci0 + 1) * 9 + j]);
    (second ? wf1b : wf2f)[idx] = v;
  } else if (b < 617) {
    int idx = (b - 356) * 256 + tid;
    if (idx < 258 * 258) {
      int y = idx / 258;
      int x = idx - y * 258;
      float4 v;
      int ay = y - 1, bx = x - 1;          // img coords for P(y,x)
      bool y0ok = (ay >= 0 && ay < 256);
      bool y1ok = (ay + 1 >= 0 && ay + 1 < 256);
      bool x0ok = (bx >= 0 && bx < 256);
      bool x1ok = (bx + 1 >= 0 && bx + 1 < 256);
      v.x = (y0ok && x0ok) ? img[(ay << 8) + bx] : 0.0f;
      v.y = (y0ok && x1ok) ? img[(ay << 8) + bx + 1] : 0.0f;
      v.z = (y1ok && x0ok) ? img[((ay + 1) << 8) + bx] : 0.0f;
      v.w = (y1ok && x1ok) ? img[((ay + 1) << 8) + bx + 1] : 0.0f;
      quadP[idx] = v;
    }
  } else {
    // wf2b B-frag: 256 ints; n>=9 columns zero.
    int d = tid & 3;
    int L = tid >> 2;
    int n = L & 15;
    int k0 = (L >> 4) * 8 + 2 * d;
    float lo = (n < 9) ? w2b[k0 * 9 + n] : 0.0f;
    float hi = (n < 9) ? w2b[(k0 + 1) * 9 + n] : 0.0f;
    wf2b[tid] = pack_rne(lo, hi);
  }
}

// ---------------------------------------------------------------------------
// Fan-beam forward projection: R1 geometry (2048 blocks, 8 chunks x 32 det,
// full occupancy) + 2-deep gather pipeline (samples i and i+8 issued
// back-to-back before consumption). FP order identical to R1.
// ---------------------------------------------------------------------------
__global__ __launch_bounds__(256) void fwdproj(
    const float4* __restrict__ quadP, const float* __restrict__ theta,
    float* __restrict__ sino) {
  __shared__ float part[8][32];
  __shared__ float cs[2];
  const int tid = threadIdx.x;
  const int a = blockIdx.x >> 5;
  const int cell = tid & 31;
  const int chunk = tid >> 5;
  const int d = ((blockIdx.x & 31) << 5) + cell;
  if (tid == 0) {
    float th = theta[a];
    cs[0] = cosf(th);
    cs[1] = sinf(th);
  }
  __syncthreads();
  const float c = cs[0], s = cs[1];
  const float u = ((float)d - 511.5f) * 2.0f;
  const float dxv = -1000.0f * c - u * s;
  const float dyv = -1000.0f * s + u * c;
  const float L = sqrtf(1.0e6f + u * u);
  const float sx = fmaf(500.0f, c, 127.5f);
  const float sy = fmaf(500.0f, s, 127.5f);

  float tlo = 0.0f, thi = 1.0f;
  if (fabsf(dxv) > 1e-6f) {
    float inv = 1.0f / dxv;
    float a0 = (-1.0f - sx) * inv, a1 = (256.0f - sx) * inv;
    tlo = fmaxf(tlo, fminf(a0, a1));
    thi = fminf(thi, fmaxf(a0, a1));
  } else if (sx <= -1.0f || sx >= 256.0f) {
    thi = -1.0f;
  }
  if (fabsf(dyv) > 1e-6f) {
    float inv = 1.0f / dyv;
    float a0 = (-1.0f - sy) * inv, a1 = (256.0f - sy) * inv;
    tlo = fmaxf(tlo, fminf(a0, a1));
    thi = fminf(thi, fmaxf(a0, a1));
  } else if (sy <= -1.0f || sy >= 256.0f) {
    thi = -1.0f;
  }
  int imin = (int)ceilf(tlo * 512.0f - 0.5f) - 1;
  imin = imin < 0 ? 0 : imin;
  int imax = (int)floorf(thi * 512.0f - 0.5f) + 1;
  imax = imax > 511 ? 511 : imax;

  float acc = 0.0f;
  int i = imin + chunk;
  for (; i + 8 <= imax; i += 16) {
    // sample i
    float t0 = ((float)i + 0.5f) * (1.0f / 512.0f);
    float cx0 = fmaf(t0, dxv, sx);
    float cy0 = fmaf(t0, dyv, sy);
    cx0 = fminf(fmaxf(cx0, -1.0f), 256.0f);
    cy0 = fminf(fmaxf(cy0, -1.0f), 256.0f);
    float xf0 = floorf(cx0), yf0 = floorf(cy0);
    float fx0 = cx0 - xf0, fy0 = cy0 - yf0;
    int idx0 = ((int)yf0 + 1) * 258 + (int)xf0 + 1;
    // sample i+8
    float t1 = ((float)(i + 8) + 0.5f) * (1.0f / 512.0f);
    float cx1 = fmaf(t1, dxv, sx);
    float cy1 = fmaf(t1, dyv, sy);
    cx1 = fminf(fmaxf(cx1, -1.0f), 256.0f);
    cy1 = fminf(fmaxf(cy1, -1.0f), 256.0f);
    float xf1 = floorf(cx1), yf1 = floorf(cy1);
    float fx1 = cx1 - xf1, fy1 = cy1 - yf1;
    int idx1 = ((int)yf1 + 1) * 258 + (int)xf1 + 1;
    // both gathers in flight before either consume
    float4 q0 = quadP[idx0];
    float4 q1 = quadP[idx1];
    {
      float gx = 1.0f - fx0, gy = 1.0f - fy0;
      acc += gy * (gx * q0.x + fx0 * q0.y) + fy0 * (gx * q0.z + fx0 * q0.w);
    }
    {
      float gx = 1.0f - fx1, gy = 1.0f - fy1;
      acc += gy * (gx * q1.x + fx1 * q1.y) + fy1 * (gx * q1.z + fx1 * q1.w);
    }
  }
  if (i <= imax) {
    float t = ((float)i + 0.5f) * (1.0f / 512.0f);
    float cx = fmaf(t, dxv, sx);
    float cy = fmaf(t, dyv, sy);
    cx = fminf(fmaxf(cx, -1.0f), 256.0f);
    cy = fminf(fmaxf(cy, -1.0f), 256.0f);
    float xf = floorf(cx), yf = floorf(cy);
    float fx = cx - xf, fy = cy - yf;
    int ix = (int)xf + 1;
    int iy = (int)yf + 1;
    float4 q = quadP[iy * 258 + ix];
    float gx = 1.0f - fx, gy = 1.0f - fy;
    acc += gy * (gx * q.x + fx * q.y) + fy * (gx * q.z + fx * q.w);
  }
  part[chunk][cell] = acc;
  __syncthreads();
  if (tid < 32) {
    float r = 0.0f;
    #pragma unroll
    for (int q = 0; q < 8; ++q) r += part[q][tid];
    sino[a * 1024 + ((blockIdx.x & 31) << 5) + tid] = r * (L * (1.0f / 512.0f));
  }
}

// ---------------------------------------------------------------------------
// Ramp filter: k-split x4, atomicAdd into diff (= -sinogram).
// NEW: windowed hext staging (1288 floats vs 4104) -- per-block filter
// window is only 1284 wide. base = 1792 - k0base keeps float4 alignment.
// hextW[m] = h[(m - 259 - k0base) & 2047]; access index m = dd0 + 256 - kk.
// ---------------------------------------------------------------------------
__global__ __launch_bounds__(256) void filt(
    const float* __restrict__ sino_pred, const float* __restrict__ h,
    float* __restrict__ diff) {
  __shared__ __align__(16) float srow[256];
  __shared__ __align__(16) float hextW[1288];
  const int a = blockIdx.x >> 2;
  const int q = blockIdx.x & 3;
  const int tid = threadIdx.x;
  const int k0base = q * 256;
  srow[tid] = sino_pred[a * 1024 + k0base + tid];
  const int shift = 259 + k0base;
  for (int m = tid; m < 1288; m += 256) hextW[m] = h[(m - shift) & 2047];
  __syncthreads();
  const int dd0 = tid * 4;
  float acc0 = 0.f, acc1 = 0.f, acc2 = 0.f, acc3 = 0.f;
  #pragma unroll 4
  for (int kk = 0; kk < 256; kk += 4) {
    float4 sv = *reinterpret_cast<const float4*>(&srow[kk]);
    int mb = dd0 + 256 - kk;
    float4 hA = *reinterpret_cast<const float4*>(&hextW[mb]);
    float4 hB = *reinterpret_cast<const float4*>(&hextW[mb + 4]);
    acc0 = fmaf(sv.x, hA.w, acc0); acc0 = fmaf(sv.y, hA.z, acc0);
    acc0 = fmaf(sv.z, hA.y, acc0); acc0 = fmaf(sv.w, hA.x, acc0);
    acc1 = fmaf(sv.x, hB.x, acc1); acc1 = fmaf(sv.y, hA.w, acc1);
    acc1 = fmaf(sv.z, hA.z, acc1); acc1 = fmaf(sv.w, hA.y, acc1);
    acc2 = fmaf(sv.x, hB.y, acc2); acc2 = fmaf(sv.y, hB.x, acc2);
    acc2 = fmaf(sv.z, hA.w, acc2); acc2 = fmaf(sv.w, hA.z, acc2);
    acc3 = fmaf(sv.x, hB.z, acc3); acc3 = fmaf(sv.y, hB.y, acc3);
    acc3 = fmaf(sv.z, hB.x, acc3); acc3 = fmaf(sv.w, hA.w, acc3);
  }
  float* o = diff + a * 1024 + dd0;
  atomicAdd(o + 0, acc0);
  atomicAdd(o + 1, acc1);
  atomicAdd(o + 2, acc2);
  atomicAdd(o + 3, acc3);
}

// ---------------------------------------------------------------------------
// Backprojection, atomic-free (R2-verified): 512 blocks x 512 threads.
// Tile 32x4 px; 4-way angle split across threads; LDS reduce; direct write
//   x_input = img - lam*(pi/64)*acc.
// ---------------------------------------------------------------------------
__global__ __launch_bounds__(512) void backproj(
    const float* __restrict__ diff, const float* __restrict__ theta,
    const float* __restrict__ lam_p, const float* __restrict__ img,
    float* __restrict__ x_input) {
  __shared__ float cst[64], snt[64];
  __shared__ float part[512];
  const int tid = threadIdx.x;
  if (tid < 64) {
    float th = theta[tid];
    cst[tid] = cosf(th);
    snt[tid] = sinf(th);
  }
  __syncthreads();
  const int tX = (blockIdx.x & 7) << 5;
  const int tY = (blockIdx.x >> 3) << 2;
  const int pl = tid & 127;             // pixel in 32x4 tile
  const int ag = tid >> 7;              // 0..3 angle group
  const int pxi = tX + (pl & 31);
  const int pyi = tY + (pl >> 5);
  const float gx = (float)pxi - 127.5f;
  const float gy = (float)pyi - 127.5f;
  float acc = 0.0f;
  for (int ai = ag * 16; ai < ag * 16 + 16; ++ai) {
    float c = cst[ai], s = snt[ai];
    float xr = gx * c + gy * s;
    float yr = gy * c - gx * s;
    float denom = 500.0f - xr;
    float inv = 1.0f / denom;
    float uu = yr * 1000.0f * inv;
    float wgt = 250000.0f * inv * inv;
    float iu = uu * 0.5f + 511.5f;
    float i0f = floorf(iu);
    float fr = iu - i0f;
    int i0 = (int)i0f;
    int c0 = min(max(i0, 0), 1023);
    int c1 = min(max(i0 + 1, 0), 1023);
    float m0 = (i0 >= 0 && i0 < 1024) ? 1.0f : 0.0f;
    float m1 = (i0 + 1 >= 0 && i0 + 1 < 1024) ? 1.0f : 0.0f;
    const float* row = diff + ai * 1024;
    float v0 = row[c0] * m0;
    float v1 = row[c1] * m1;
    acc += (v0 * (1.0f - fr) + v1 * fr) * wgt;
  }
  part[tid] = acc;
  __syncthreads();
  if (tid < 128) {
    float sum = part[tid] + part[tid + 128] + part[tid + 256] + part[tid + 384];
    int p = ((tY + (tid >> 5)) << 8) + tX + (tid & 31);
    x_input[p] = img[p] - lam_p[0] * 0.04908738521234052f * sum;
  }
}

// ---------------------------------------------------------------------------
// conv12f (R1-verified): conv1f + relu (VALU) + conv2f (MFMA, shared B-frag).
// 32x4 tiles (512 blocks) + group-major LDS layout (all b128 LDS traffic).
// Output PIXEL-MAJOR packed bf16 pairs: xfp[gpos*16 + c2] (int2 stores).
// ---------------------------------------------------------------------------
__global__ __launch_bounds__(256) void conv12f(
    const float* __restrict__ x_input, const float* __restrict__ w1f,
    const int* __restrict__ wf2f, int* __restrict__ xfp) {
  __shared__ float xin[8][36];
  __shared__ __align__(16) int htile[3264];   // 4 groups x 204 px x int4
  const int tid = threadIdx.x;
  const int lane = tid & 63;
  const int wave = tid >> 6;
  const int tX = (blockIdx.x & 7) << 5;
  const int tY = (blockIdx.x >> 3) << 2;

  FragI4 wf[2][9];
  const int4* wfg = (const int4*)wf2f;
  #pragma unroll
  for (int mt = 0; mt < 2; ++mt)
    #pragma unroll
    for (int j = 0; j < 9; ++j) wf[mt][j].i4 = wfg[(j * 2 + mt) * 64 + lane];

  for (int idx = tid; idx < 288; idx += 256) {
    int sy = idx / 36;
    int sx = idx - sy * 36;
    int gy = tY + sy - 2, gx = tX + sx - 2;
    xin[sy][sx] = (gy >= 0 && gy < 256 && gx >= 0 && gx < 256)
                      ? x_input[(gy << 8) + gx] : 0.0f;
  }
  __syncthreads();

  for (int pos = tid; pos < 204; pos += 256) {
    int yy = pos / 34;
    int xx = pos - yy * 34;
    int hy = tY + yy - 1, hx = tX + xx - 1;
    bool hin = (hy >= 0 && hy < 256 && hx >= 0 && hx < 256);
    float v[9];
    #pragma unroll
    for (int dy = 0; dy < 3; ++dy)
      #pragma unroll
      for (int dx = 0; dx < 3; ++dx) v[dy * 3 + dx] = xin[yy + dy][xx + dx];
    int packs[16];
    #pragma unroll
    for (int c2 = 0; c2 < 16; ++c2) {
      float r0 = 0.0f, r1 = 0.0f;
      #pragma unroll
      for (int j = 0; j < 9; ++j) {
        r0 = fmaf(v[j], w1f[(2 * c2) * 9 + j], r0);
        r1 = fmaf(v[j], w1f[(2 * c2 + 1) * 9 + j], r1);
      }
      r0 = hin ? fmaxf(r0, 0.0f) : 0.0f;
      r1 = hin ? fmaxf(r1, 0.0f) : 0.0f;
      packs[c2] = pack_rne(r0, r1);
    }
    #pragma unroll
    for (int g = 0; g < 4; ++g)
      *reinterpret_cast<int4*>(&htile[g * 816 + pos * 4]) =
          make_int4(packs[4 * g], packs[4 * g + 1],
                    packs[4 * g + 2], packs[4 * g + 3]);
  }
  __syncthreads();

  const int y = wave;
  const int n = lane & 15;
  const int q = lane >> 4;
  const int qb = q * 816;
  for (int xt = 0; xt < 2; ++xt) {
    const int x0 = xt << 4;
    f32x4 acc0 = {0.f, 0.f, 0.f, 0.f};
    f32x4 acc1 = {0.f, 0.f, 0.f, 0.f};
    #pragma unroll
    for (int j = 0; j < 9; ++j) {
      int dy = j / 3, dx = j - dy * 3;
      int pb = (y + dy) * 34 + x0 + dx + n;
      FragI4 bf;
      bf.i4 = *reinterpret_cast<const int4*>(&htile[qb + pb * 4]);
      acc0 = __builtin_amdgcn_mfma_f32_16x16x32_bf16(wf[0][j].v, bf.v, acc0, 0, 0, 0);
      acc1 = __builtin_amdgcn_mfma_f32_16x16x32_bf16(wf[1][j].v, bf.v, acc1, 0, 0, 0);
    }
    const int gpos = ((tY + y) << 8) + tX + x0 + n;
    int2* xp = (int2*)(xfp + (gpos << 4));
    xp[q]     = make_int2(pack_rne(acc0[0], acc0[1]), pack_rne(acc0[2], acc0[3]));
    xp[4 + q] = make_int2(pack_rne(acc1[0], acc1[1]), pack_rne(acc1[2], acc1[3]));
  }
}

// ---------------------------------------------------------------------------
// branch_tail (R1-verified): group-major LDS layout [g][px][int4]; all
// fragment traffic is aligned b128/b64. LDS 60.4 KB, 2 blocks/CU.
// ---------------------------------------------------------------------------
__global__ __launch_bounds__(256) void branch_tail(
    const int* __restrict__ xfp, const int* __restrict__ wf1b,
    const int* __restrict__ wf2b, const float* __restrict__ thr_p,
    const float* __restrict__ x_input, float* __restrict__ out) {
  __shared__ __align__(16) int ldsX[8704];   // 4 groups x 544 px x int4
  __shared__ __align__(16) int ldsD[6400];   // 4 groups x 400 px x int4
  float* ldsP = (float*)ldsX;                // aliases ldsX after phase A
  const int tid = threadIdx.x;
  const int lane = tid & 63;
  const int wave = tid >> 6;
  const int branch = blockIdx.x >> 8;
  const int tileb = blockIdx.x & 255;
  const int tX = (tileb & 3) << 6;
  const int tY = (tileb >> 2) << 2;
  const float thr = thr_p[0];
  const bool soft = (branch == 0);

  FragI4 wf[2][9];
  const int4* wfg = (const int4*)wf1b;
  #pragma unroll
  for (int mt = 0; mt < 2; ++mt)
    #pragma unroll
    for (int j = 0; j < 9; ++j) wf[mt][j].i4 = wfg[(j * 2 + mt) * 64 + lane];
  FragI4 wb;
  wb.i4 = ((const int4*)wf2b)[lane];

  // zero D rows 396..399 (read by phase P, never written by phase A)
  if (tid < 16) {
    int g = tid >> 2, px = 396 + (tid & 3);
    *reinterpret_cast<int4*>(&ldsD[g * 1600 + px * 4]) = make_int4(0, 0, 0, 0);
  }

  // staging: <=3 px/thread, 4 int4 global loads + 4 b128 LDS writes each.
  #pragma unroll
  for (int t = 0; t < 3; ++t) {
    int p = tid + t * 256;
    if (p < 544) {
      int sy = p / 68;
      int sx = p - sy * 68;
      int gy = tY + sy - 2, gx = tX + sx - 2;
      bool ok = ((unsigned)gy < 256u) && ((unsigned)gx < 256u);
      I4U w[4];
      if (ok) {
        const int4* src = (const int4*)(xfp + (((gy << 8) + gx) << 4));
        w[0].i4 = src[0]; w[1].i4 = src[1]; w[2].i4 = src[2]; w[3].i4 = src[3];
      } else {
        w[0].i4 = w[1].i4 = w[2].i4 = w[3].i4 = make_int4(0, 0, 0, 0);
      }
      #pragma unroll
      for (int g = 0; g < 4; ++g) {
        if (soft) {
          #pragma unroll
          for (int k = 0; k < 4; ++k) {
            int v = w[g].i[k];
            float lo = __uint_as_float(((unsigned)v) << 16);
            float hi = __uint_as_float(((unsigned)v) & 0xFFFF0000u);
            lo = fmaxf(lo - thr, 0.0f) + fminf(lo + thr, 0.0f);
            hi = fmaxf(hi - thr, 0.0f) + fminf(hi + thr, 0.0f);
            w[g].i[k] = pack_rne(lo, hi);
          }
        }
        *reinterpret_cast<int4*>(&ldsX[g * 2176 + p * 4]) = w[g].i4;
      }
    }
  }
  __syncthreads();

  // phase A: D = relu(conv1b) over region rx -1..64, ry -1..4 (16px units).
  const int n = lane & 15;
  const int q = lane >> 4;
  const int rxtab[5] = {-1, 15, 31, 47, 49};
  for (int t = wave; t < 30; t += 4) {
    int trow = t / 5;
    int ry = trow - 1;
    int rx0 = rxtab[t - trow * 5];
    int rxn = rx0 + n;
    bool inimg = ((unsigned)(tX + rxn) < 256u) && ((unsigned)(tY + ry) < 256u);
    int pxD = (ry + 1) * 66 + rxn + 1;
    f32x4 acc0 = {0.f, 0.f, 0.f, 0.f};
    f32x4 acc1 = {0.f, 0.f, 0.f, 0.f};
    #pragma unroll
    for (int j = 0; j < 9; ++j) {
      int dy = j / 3, dx = j - dy * 3;
      int pb = (ry + 1 + dy) * 68 + rx0 + 1 + dx + n;
      FragI4 bf;
      bf.i4 = *reinterpret_cast<const int4*>(&ldsX[q * 2176 + pb * 4]);
      acc0 = __builtin_amdgcn_mfma_f32_16x16x32_bf16(wf[0][j].v, bf.v, acc0, 0, 0, 0);
      acc1 = __builtin_amdgcn_mfma_f32_16x16x32_bf16(wf[1][j].v, bf.v, acc1, 0, 0, 0);
    }
    float a00 = inimg ? fmaxf(acc0[0], 0.0f) : 0.0f;
    float a01 = inimg ? fmaxf(acc0[1], 0.0f) : 0.0f;
    float a02 = inimg ? fmaxf(acc0[2], 0.0f) : 0.0f;
    float a03 = inimg ? fmaxf(acc0[3], 0.0f) : 0.0f;
    float a10 = inimg ? fmaxf(acc1[0], 0.0f) : 0.0f;
    float a11 = inimg ? fmaxf(acc1[1], 0.0f) : 0.0f;
    float a12 = inimg ? fmaxf(acc1[2], 0.0f) : 0.0f;
    float a13 = inimg ? fmaxf(acc1[3], 0.0f) : 0.0f;
    *reinterpret_cast<int2*>(
        &ldsD[(q >> 1) * 1600 + pxD * 4 + (q & 1) * 2]) =
        make_int2(pack_rne(a00, a01), pack_rne(a02, a03));
    *reinterpret_cast<int2*>(
        &ldsD[(2 + (q >> 1)) * 1600 + pxD * 4 + (q & 1) * 2]) =
        make_int2(pack_rne(a10, a11), pack_rne(a12, a13));
  }
  __syncthreads();

  // phase P: 25 M-tiles of 16 px; one MFMA each (A=D, B=wf2b).
  for (int t = wave; t < 25; t += 4) {
    int pbase = t << 4;
    FragI4 af;
    af.i4 = *reinterpret_cast<const int4*>(&ldsD[q * 1600 + (pbase + n) * 4]);
    f32x4 acc = {0.f, 0.f, 0.f, 0.f};
    acc = __builtin_amdgcn_mfma_f32_16x16x32_bf16(af.v, wb.v, acc, 0, 0, 0);
    #pragma unroll
    for (int r = 0; r < 4; ++r)
      ldsP[(pbase + q * 4 + r) * 17 + n] = acc[r];
  }
  __syncthreads();

  // epilogue: out[p] = sum_j P[p+off(j)][j]
  const int px = tid & 63, py = tid >> 6;
  float acc = 0.0f;
  #pragma unroll
  for (int j = 0; j < 9; ++j) {
    int dy = j / 3, dx = j - dy * 3;
    int rp = (py + dy) * 66 + px + dx;
    acc += ldsP[rp * 17 + j];
  }
  const int p = ((tY + py) << 8) + tX + px;
  if (branch == 0) out[p] = acc;
  else out[65536 + p] = acc - x_input[p];
}

extern "C" void kernel_launch(void* const* d_in, const int* in_sizes, int n_in,
                              void* d_out, int out_size, void* d_ws, size_t ws_size,
                              hipStream_t stream) {
  const float* x       = (const float*)d_in[0];
  const float* theta   = (const float*)d_in[1];
  const float* sino_in = (const float*)d_in[2];
  const float* lam     = (const float*)d_in[3];
  const float* thr     = (const float*)d_in[4];
  const float* w_c1f   = (const float*)d_in[5];
  const float* w_c2f   = (const float*)d_in[6];
  const float* w_c1b   = (const float*)d_in[7];
  const float* w_c2b   = (const float*)d_in[8];
  float* out = (float*)d_out;
  float* ws  = (float*)d_ws;

  float* h         = ws + H_OFF;
  float* sino_pred = ws + SINO_OFF;
  float* diff      = ws + DIFF_OFF;
  float* x_input   = ws + XIN_OFF;
  int*   wf2f      = (int*)(ws + WF2F_OFF);
  int*   wf1b      = (int*)(ws + WF1B_OFF);
  int*   wf2b      = (int*)(ws + WF2B_OFF);
  float4* quadP    = (float4*)(ws + BUFA_OFF);   // dead once fwdproj completes
  int*   xfp       = (int*)(ws + BUFB_OFF);      // x_forward, pixel-major bf16

  setup_kernel<<<618, 256, 0, stream>>>(sino_in, w_c2f, w_c1b, w_c2b, x, h,
                                        diff, wf2f, wf1b, wf2b, quadP);
  fwdproj<<<2048, 256, 0, stream>>>(quadP, theta, sino_pred);
  filt<<<256, 256, 0, stream>>>(sino_pred, h, diff);
  backproj<<<512, 512, 0, stream>>>(diff, theta, lam, x, x_input);
  conv12f<<<512, 256, 0, stream>>>(x_input, w_c1f, wf2f, xfp);
  branch_tail<<<512, 256, 0, stream>>>(xfp, wf1b, wf2b, thr, x_input, out);
}